// Round 1
// baseline (690.430 us; speedup 1.0000x reference)
//
#include <hip/hip_runtime.h>

typedef __attribute__((ext_vector_type(8))) short short8;
typedef __attribute__((ext_vector_type(4))) float f32x4;

__device__ __forceinline__ unsigned short f2bf(float f) {
  unsigned u = __float_as_uint(f);
  u += 0x7FFF + ((u >> 16) & 1);   // RNE to bf16
  return (unsigned short)(u >> 16);
}
__device__ __forceinline__ float bf2f(unsigned short s) {
  return __uint_as_float(((unsigned)s) << 16);
}
__device__ __forceinline__ f32x4 mfma16(short8 a, short8 b, f32x4 c) {
  return __builtin_amdgcn_mfma_f32_16x16x32_bf16(a, b, c, 0, 0, 0);
}

// ---------------- converts ----------------
__global__ void cvt_x_kernel(const float* __restrict__ in, unsigned short* __restrict__ out, int n) {
  int i = blockIdx.x * 256 + threadIdx.x;
  if (i < n) out[i] = f2bf(in[i]);
}

// in: K x N row-major (f32) -> out: N x K row-major (bf16)
__global__ void transpose_cvt_kernel(const float* __restrict__ in, unsigned short* __restrict__ out,
                                     int K, int N) {
  int i = blockIdx.x * 256 + threadIdx.x;
  if (i < K * N) {
    int n = i / K, k = i - n * K;
    out[i] = f2bf(in[(size_t)k * N + n]);
  }
}

// ---------------- GEMM: C[M,N] = A[M,K] @ BT[N,K]^T + bias ----------------
// MODE 0: bf16 row-major out; MODE 1: f32 row-major out; MODE 2: bf16 out in
// V-transposed layout [(b*8+h)*256+d][1024 pos]
template<int MODE>
__global__ __launch_bounds__(256, 2) void gemm128(const unsigned short* __restrict__ A,
    const unsigned short* __restrict__ BT, const float* __restrict__ bias,
    void* __restrict__ Cout, int Mdim, int Ndim, int Kdim) {
  __shared__ short As[128 * 40];   // +8 pad: 80B row stride, 16B aligned, conflict-light
  __shared__ short Bs[128 * 40];
  const int tid = threadIdx.x;
  const int wid = tid >> 6, lane = tid & 63;
  const int l15 = lane & 15, lg = lane >> 4;
  const int m0 = blockIdx.y * 128, n0 = blockIdx.x * 128;
  const int wr = (wid >> 1) * 64, wc = (wid & 1) * 64;
  const f32x4 z = {0.f, 0.f, 0.f, 0.f};
  f32x4 acc[4][4];
#pragma unroll
  for (int mi = 0; mi < 4; ++mi)
#pragma unroll
    for (int ni = 0; ni < 4; ++ni) acc[mi][ni] = z;

  for (int kt = 0; kt < Kdim; kt += 32) {
#pragma unroll
    for (int it = 0; it < 2; ++it) {
      int c = tid + it * 256;
      int row = c >> 2, c8 = (c & 3) * 8;
      *(short8*)&As[row * 40 + c8] = *(const short8*)(A + (size_t)(m0 + row) * Kdim + kt + c8);
      *(short8*)&Bs[row * 40 + c8] = *(const short8*)(BT + (size_t)(n0 + row) * Kdim + kt + c8);
    }
    __syncthreads();
    short8 a[4], b[4];
#pragma unroll
    for (int mi = 0; mi < 4; ++mi) a[mi] = *(const short8*)&As[(wr + mi * 16 + l15) * 40 + lg * 8];
#pragma unroll
    for (int ni = 0; ni < 4; ++ni) b[ni] = *(const short8*)&Bs[(wc + ni * 16 + l15) * 40 + lg * 8];
#pragma unroll
    for (int mi = 0; mi < 4; ++mi)
#pragma unroll
      for (int ni = 0; ni < 4; ++ni)
        acc[mi][ni] = mfma16(a[mi], b[ni], acc[mi][ni]);
    __syncthreads();
  }
#pragma unroll
  for (int mi = 0; mi < 4; ++mi)
#pragma unroll
    for (int ni = 0; ni < 4; ++ni)
#pragma unroll
      for (int e = 0; e < 4; ++e) {
        int gm = m0 + wr + mi * 16 + lg * 4 + e;     // D row = (lane>>4)*4+e  [m89-verified]
        int gn = n0 + wc + ni * 16 + l15;            // D col = lane&15
        float v = acc[mi][ni][e] + bias[gn];
        if (MODE == 0) {
          ((unsigned short*)Cout)[(size_t)gm * Ndim + gn] = f2bf(v);
        } else if (MODE == 1) {
          ((float*)Cout)[(size_t)gm * Ndim + gn] = v;
        } else {
          int b_ = gm >> 10, pos = gm & 1023;
          int h = gn >> 8, d = gn & 255;
          ((unsigned short*)Cout)[((size_t)((b_ * 8 + h) * 256 + d)) * 1024 + pos] = f2bf(v);
        }
      }
}

// ---------------- separable position bias: R[bh][q][32], C[bh][q][32] ----------------
__global__ void bias_kernel(const unsigned short* __restrict__ Q, const float* __restrict__ row_tab,
    const float* __restrict__ col_tab, float* __restrict__ Rb, float* __restrict__ Cb) {
  const int q = blockIdx.x, bh = blockIdx.y;
  const int b = bh >> 3, h = bh & 7;
  const int i = q >> 5, j = q & 31;
  __shared__ __align__(16) float qrow[256];
  const int t = threadIdx.x;  // 64 threads
  const unsigned short* qp = Q + (size_t)(b * 1024 + q) * 2048 + h * 256;
#pragma unroll
  for (int c = 0; c < 4; ++c) qrow[t + c * 64] = bf2f(qp[t + c * 64]);
  __syncthreads();
  float acc = 0.f;
  if (t < 32) {
    const float4* tab4 = (const float4*)(row_tab + (size_t)(t - i + 31) * 128);
    const float4* q4 = (const float4*)qrow;
#pragma unroll 8
    for (int d = 0; d < 32; ++d) {
      float4 a = q4[d], bb = tab4[d];
      acc += a.x * bb.x + a.y * bb.y + a.z * bb.z + a.w * bb.w;
    }
    Rb[((size_t)bh * 1024 + q) * 32 + t] = acc;
  } else {
    int l = t - 32;
    const float4* tab4 = (const float4*)(col_tab + (size_t)(j - l + 31) * 128);
    const float4* q4 = (const float4*)(qrow + 128);
#pragma unroll 8
    for (int d = 0; d < 32; ++d) {
      float4 a = q4[d], bb = tab4[d];
      acc += a.x * bb.x + a.y * bb.y + a.z * bb.z + a.w * bb.w;
    }
    Cb[((size_t)bh * 1024 + q) * 32 + l] = acc;
  }
}

// ---------------- flash attention with separable bias ----------------
// grid (16 qblk, 64 bh), 256 thr = 4 waves, 16 queries/wave, KV tile = 64
__global__ __launch_bounds__(256, 2) void attn_kernel(const unsigned short* __restrict__ Q,
    const unsigned short* __restrict__ K, const unsigned short* __restrict__ Vt,
    const float* __restrict__ Rb, const float* __restrict__ Cb,
    unsigned short* __restrict__ Att) {
  __shared__ short Klds[64 * 256];       // [key][d], XOR-swizzled (G4: avoid 32-way conflict)
  __shared__ short Vlds[256 * 72];       // [d][key], +8 pad
  __shared__ short Plds[4][16 * 72];     // per-wave P [q][key], +8 pad
  const int qblk = blockIdx.x, bh = blockIdx.y;
  const int b = bh >> 3, h = bh & 7;
  const int tid = threadIdx.x, wid = tid >> 6, lane = tid & 63;
  const int l15 = lane & 15, lg = lane >> 4;
  const int q0 = qblk * 64 + wid * 16;

  short8 qa[8];
  {
    const unsigned short* qp = Q + (size_t)(b * 1024 + q0 + l15) * 2048 + h * 256;
#pragma unroll
    for (int kk = 0; kk < 8; ++kk) qa[kk] = *(const short8*)(qp + kk * 32 + lg * 8);
  }
  const f32x4 z = {0.f, 0.f, 0.f, 0.f};
  f32x4 o[16];
#pragma unroll
  for (int nf = 0; nf < 16; ++nf) o[nf] = z;
  float m_r[4], l_r[4];
#pragma unroll
  for (int e = 0; e < 4; ++e) { m_r[e] = -1e30f; l_r[e] = 0.f; }

  const unsigned short* kbase = K + (size_t)(b * 1024) * 2048 + h * 256;
  const unsigned short* vbase = Vt + (size_t)bh * 256 * 1024;
  const float* rbp = Rb + ((size_t)bh * 1024 + q0) * 32;
  const float* cbp = Cb + ((size_t)bh * 1024 + q0) * 32;
  short* pl = &Plds[wid][0];

  for (int t = 0; t < 16; ++t) {
    __syncthreads();
    // stage K tile (64 keys x 256 d)
#pragma unroll
    for (int it = 0; it < 8; ++it) {
      int c = tid + it * 256;
      int key = c >> 5, c8 = (c & 31) * 8;
      short8 v = *(const short8*)(kbase + (size_t)(t * 64 + key) * 2048 + c8);
      int off = ((key * 256 + c8) * 2) ^ ((key & 7) << 4);
      *(short8*)((char*)Klds + off) = v;
    }
    // stage V tile transposed (256 d x 64 keys), from pre-transposed global V
#pragma unroll
    for (int it = 0; it < 8; ++it) {
      int c = tid + it * 256;
      int d = c >> 3, k8 = (c & 7) * 8;
      short8 v = *(const short8*)(vbase + (size_t)d * 1024 + t * 64 + k8);
      *(short8*)&Vlds[d * 72 + k8] = v;
    }
    __syncthreads();
    // S = Q @ K^T  (16q x 64key)
    f32x4 s[4];
#pragma unroll
    for (int nf = 0; nf < 4; ++nf) {
      f32x4 a = z;
      int key = nf * 16 + l15;
      int swz = (key & 7) << 4;
#pragma unroll
      for (int kk = 0; kk < 8; ++kk) {
        int off = ((key * 256 + kk * 32 + lg * 8) * 2) ^ swz;
        short8 kb = *(const short8*)((char*)Klds + off);
        a = mfma16(qa[kk], kb, a);
      }
      s[nf] = a;
    }
    // separable bias: key = t*64 + nf*16 + l15 -> krow = 2t+(nf>>1), lcol = (nf&1)*16+l15
#pragma unroll
    for (int nf = 0; nf < 4; ++nf)
#pragma unroll
      for (int e = 0; e < 4; ++e) {
        int ql = lg * 4 + e;
        s[nf][e] += rbp[(size_t)ql * 32 + t * 2 + (nf >> 1)]
                  + cbp[(size_t)ql * 32 + (nf & 1) * 16 + l15];
      }
    // online softmax (rows live in 16-lane groups)
#pragma unroll
    for (int e = 0; e < 4; ++e) {
      float tm = fmaxf(fmaxf(s[0][e], s[1][e]), fmaxf(s[2][e], s[3][e]));
      tm = fmaxf(tm, __shfl_xor(tm, 1));
      tm = fmaxf(tm, __shfl_xor(tm, 2));
      tm = fmaxf(tm, __shfl_xor(tm, 4));
      tm = fmaxf(tm, __shfl_xor(tm, 8));
      float mn = fmaxf(m_r[e], tm);
      float sc = __expf(m_r[e] - mn);
      m_r[e] = mn;
      float ps = 0.f;
#pragma unroll
      for (int nf = 0; nf < 4; ++nf) {
        float p = __expf(s[nf][e] - mn);
        s[nf][e] = p;
        ps += p;
      }
      ps += __shfl_xor(ps, 1); ps += __shfl_xor(ps, 2);
      ps += __shfl_xor(ps, 4); ps += __shfl_xor(ps, 8);
      l_r[e] = l_r[e] * sc + ps;
#pragma unroll
      for (int nf = 0; nf < 16; ++nf) o[nf][e] *= sc;
    }
    // P -> bf16 -> per-wave LDS (A-fragment layout for PV)
#pragma unroll
    for (int nf = 0; nf < 4; ++nf)
#pragma unroll
      for (int e = 0; e < 4; ++e) {
        int ql = lg * 4 + e;
        pl[ql * 72 + nf * 16 + l15] = (short)f2bf(s[nf][e]);
      }
    __syncthreads();   // cross-lane P handoff (prevents per-thread alias-based reorder)
    // O += P @ V
#pragma unroll
    for (int s2 = 0; s2 < 2; ++s2) {
      short8 pa = *(const short8*)&pl[l15 * 72 + s2 * 32 + lg * 8];
#pragma unroll
      for (int nf = 0; nf < 16; ++nf) {
        short8 vb = *(const short8*)&Vlds[(nf * 16 + l15) * 72 + s2 * 32 + lg * 8];
        o[nf] = mfma16(pa, vb, o[nf]);
      }
    }
  }
  unsigned short* op = Att + (size_t)(b * 1024 + q0) * 2048 + h * 256;
#pragma unroll
  for (int nf = 0; nf < 16; ++nf)
#pragma unroll
    for (int e = 0; e < 4; ++e) {
      int ql = lg * 4 + e;
      op[(size_t)ql * 2048 + nf * 16 + l15] = f2bf(o[nf][e] / l_r[e]);
    }
}

// ---------------- launch ----------------
extern "C" void kernel_launch(void* const* d_in, const int* in_sizes, int n_in,
                              void* d_out, int out_size, void* d_ws, size_t ws_size,
                              hipStream_t stream) {
  (void)in_sizes; (void)n_in; (void)out_size;
  const float* x   = (const float*)d_in[0];
  const float* Kw  = (const float*)d_in[1];
  const float* Kb  = (const float*)d_in[2];
  const float* Qw  = (const float*)d_in[3];
  const float* Qb  = (const float*)d_in[4];
  const float* Vw  = (const float*)d_in[5];
  const float* Vb  = (const float*)d_in[6];
  const float* Pw  = (const float*)d_in[7];
  const float* Pb  = (const float*)d_in[8];
  const float* row_tab = (const float*)d_in[9];
  const float* col_tab = (const float*)d_in[10];
  float* out = (float*)d_out;

  char* ws = (char*)d_ws;
  size_t off = 0;
  auto alloc = [&](size_t bytes) { char* p = ws + off; off += bytes; return p; };
  unsigned short* Xb   = (unsigned short*)alloc((size_t)8192 * 256 * 2);
  unsigned short* WqT  = (unsigned short*)alloc((size_t)2048 * 256 * 2);
  unsigned short* WkT  = (unsigned short*)alloc((size_t)2048 * 256 * 2);
  unsigned short* WvT  = (unsigned short*)alloc((size_t)2048 * 256 * 2);
  unsigned short* PwT  = (unsigned short*)alloc((size_t)256 * 2048 * 2);
  unsigned short* Qg   = (unsigned short*)alloc((size_t)8192 * 2048 * 2);
  unsigned short* Kg   = (unsigned short*)alloc((size_t)8192 * 2048 * 2);
  unsigned short* VtG  = (unsigned short*)alloc((size_t)8192 * 2048 * 2);
  unsigned short* AttG = (unsigned short*)alloc((size_t)8192 * 2048 * 2);
  float* Rb = (float*)alloc((size_t)64 * 1024 * 32 * 4);
  float* Cb = (float*)alloc((size_t)64 * 1024 * 32 * 4);
  if (off > ws_size) return;  // workspace too small: bail rather than fault

  cvt_x_kernel<<<8192, 256, 0, stream>>>(x, Xb, 8192 * 256);
  transpose_cvt_kernel<<<2048, 256, 0, stream>>>(Qw, WqT, 256, 2048);
  transpose_cvt_kernel<<<2048, 256, 0, stream>>>(Kw, WkT, 256, 2048);
  transpose_cvt_kernel<<<2048, 256, 0, stream>>>(Vw, WvT, 256, 2048);
  transpose_cvt_kernel<<<2048, 256, 0, stream>>>(Pw, PwT, 2048, 256);

  gemm128<0><<<dim3(16, 64), 256, 0, stream>>>(Xb, WqT, Qb, Qg, 8192, 2048, 256);
  gemm128<0><<<dim3(16, 64), 256, 0, stream>>>(Xb, WkT, Kb, Kg, 8192, 2048, 256);
  gemm128<2><<<dim3(16, 64), 256, 0, stream>>>(Xb, WvT, Vb, VtG, 8192, 2048, 256);

  bias_kernel<<<dim3(1024, 64), 64, 0, stream>>>(Qg, row_tab, col_tab, Rb, Cb);
  attn_kernel<<<dim3(16, 64), 256, 0, stream>>>(Qg, Kg, VtG, Rb, Cb, AttG);
  gemm128<1><<<dim3(2, 64), 256, 0, stream>>>(AttG, PwT, Pb, out, 8192, 256, 2048);
}